// Round 13
// baseline (152.030 us; speedup 1.0000x reference)
//
#include <hip/hip_runtime.h>
#include <stdint.h>
#include <stddef.h>

// ---------------------------------------------------------------------------
// out = softmax(x Wq+bq @ (x Wk+bk)^T) * sqrt(512) @ (x Wv+bv)
// B=8, N=2048, D=DK=DV=512, fp32 I/O.
// Round 13: fold x fp32->f16 conversion into k_proj's A-staging (reg-stage
// with identical phys LDS layout; W stays on global_load_lds).  Deletes
// k_conv_x (~15us of pure HBM dtype-copy).  qk2/pv7 identical to round 12.
// ws layout (B): Q 16777216, K 33554432, Vt 50331648,
//   P 67108864 (67108864), mG 134217728 (2097152), lG 136314880 (2097152),
//   Wt 201326592 (1572864).  total <= 202899456.
// ---------------------------------------------------------------------------

typedef _Float16 f16_t;
typedef _Float16 f16x8 __attribute__((ext_vector_type(8)));
typedef float    f32x4 __attribute__((ext_vector_type(4)));

__device__ __forceinline__ f32x4 mfma_h(f16x8 a, f16x8 b, f32x4 c) {
  // D frag: col = lane&15, row = (lane>>4)*4 + reg
  return __builtin_amdgcn_mfma_f32_16x16x32_f16(a, b, c, 0, 0, 0);
}

__device__ __forceinline__ void gl_lds16(const void* g, void* lds) {
  __builtin_amdgcn_global_load_lds(
      (const __attribute__((address_space(1))) unsigned int*)g,
      (__attribute__((address_space(3))) unsigned int*)lds, 16, 0, 0);
}

// Stage a [128][64] f16 tile (16 KB), 4-wave (256-thr) cooperative.
// Linear LDS dest; source pre-swizzled: phys slot s of row r holds logical
// slot s^(r&7) (16B slots, 8 per 128B row).
__device__ __forceinline__ void stage_tile(f16_t* lds, const f16_t* g,
                                           size_t gstride, int wave, int lane) {
  const int l8 = lane >> 3;
  const int lslot = (lane & 7) ^ l8;
  #pragma unroll
  for (int c = 0; c < 4; ++c) {
    const int chunk = wave * 4 + c;
    const int row = chunk * 8 + l8;
    gl_lds16(g + (size_t)row * gstride + lslot * 8, lds + chunk * 512);
  }
}

// Stage a [64][64] f16 tile (8 KB): 8 chunks, 2 per wave (256 thr).
__device__ __forceinline__ void stage_tile64(f16_t* lds, const f16_t* g,
                                             size_t gstride, int wave, int lane) {
  const int l8 = lane >> 3;
  const int lslot = (lane & 7) ^ l8;
  #pragma unroll
  for (int c = 0; c < 2; ++c) {
    const int chunk = wave * 2 + c;
    const int row = chunk * 8 + l8;
    gl_lds16(g + (size_t)row * gstride + lslot * 8, lds + chunk * 512);
  }
}

// Reg-stage a [128][64] tile from FP32 global, converting to f16, writing
// the SAME phys layout stage_tile produces (slot (l&7)^(l>>3) of row
// chunk*8+(l>>3) -> lds[chunk*512 + lane*8]).
__device__ __forceinline__ void stage_tile_cvt(f16_t* lds, const float* g,
                                               size_t gstride, int wave,
                                               int lane) {
  const int l8 = lane >> 3;
  const int lslot = (lane & 7) ^ l8;
  #pragma unroll
  for (int c = 0; c < 4; ++c) {
    const int chunk = wave * 4 + c;
    const int row = chunk * 8 + l8;
    const float* src = g + (size_t)row * gstride + lslot * 8;
    const float4 a = *(const float4*)&src[0];
    const float4 b = *(const float4*)&src[4];
    f16x8 h;
    h[0] = (f16_t)a.x; h[1] = (f16_t)a.y; h[2] = (f16_t)a.z; h[3] = (f16_t)a.w;
    h[4] = (f16_t)b.x; h[5] = (f16_t)b.y; h[6] = (f16_t)b.z; h[7] = (f16_t)b.w;
    *(f16x8*)&lds[chunk * 512 + lane * 8] = h;
  }
}

// Swizzled fragment read: logical (row R, 8 elems at col slot*8)
__device__ __forceinline__ f16x8 lds_frag(const f16_t* buf, int R, int slot) {
  return *(const f16x8*)&buf[R * 64 + (((slot ^ (R & 7)) & 7) << 3)];
}

// XCD-chunked work remap (requires nwg % 8 == 0)
__device__ __forceinline__ int xcd_swz(int id, int nwg) {
  return (id & 7) * (nwg >> 3) + (id >> 3);
}

// ---------------------------------------------------------------------------
// transpose+convert W -> Wt[p][n][k] f16
__global__ __launch_bounds__(256) void k_conv_w(const float* __restrict__ Wq,
                                                const float* __restrict__ Wk,
                                                const float* __restrict__ Wv,
                                                f16_t* __restrict__ Wt) {
  __shared__ float t[64][65];
  const int p = blockIdx.z;
  const float* __restrict__ W = (p == 0) ? Wq : (p == 1) ? Wk : Wv;
  const int n0 = blockIdx.x * 64, k0 = blockIdx.y * 64;
  const int tx = threadIdx.x & 63, ty = threadIdx.x >> 6;
  #pragma unroll
  for (int j = 0; j < 16; ++j)
    t[ty * 16 + j][tx] = W[(size_t)(k0 + ty * 16 + j) * 512 + n0 + tx];
  __syncthreads();
  #pragma unroll
  for (int j = 0; j < 16; ++j) {
    const int nl = ty * 16 + j;
    Wt[(size_t)p * 262144 + (size_t)(n0 + nl) * 512 + k0 + tx] =
        (f16_t)t[tx][nl];
  }
}

// ---------------------------------------------------------------------------
// Projection: flat grid 1536 (xcd-swizzled -> mt*12+jt).  Single fp16 MFMA.
// panels 0-3 Q, 4-7 K, 8-11 V (V transposed to Vt[b][dv][n]).
// A staged straight from fp32 x with in-flight conversion (reg path);
// W staged via global_load_lds (latency hides under the A-convert VALU).
// ---------------------------------------------------------------------------
__global__ __launch_bounds__(256, 4) void k_proj(
    const float* __restrict__ x, const f16_t* __restrict__ Wt,
    const float* __restrict__ bq, const float* __restrict__ bk,
    const float* __restrict__ bv,
    f16_t* __restrict__ Q, f16_t* __restrict__ K, f16_t* __restrict__ Vt)
{
  __shared__ __align__(16) unsigned char smem[34816];  // A,B tiles / vtl
  f16_t* A = (f16_t*)smem;
  f16_t* B = (f16_t*)(smem + 16384);

  const int wg = xcd_swz(blockIdx.x, 1536);
  const int mt = wg / 12, jt = wg % 12;
  const int which = jt >> 2;            // 0=Q 1=K 2=V
  const int jb = (jt & 3) * 128;

  const int tid = threadIdx.x, lane = tid & 63, wave = tid >> 6;
  const int wr = wave >> 1, wc = wave & 1, l15 = lane & 15, lg = lane >> 4;
  const int rowbase = mt * 128;

  const f16_t* Wbase = Wt + (size_t)which * 262144 + (size_t)jb * 512;

  f32x4 acc[4][4] = {};

  for (int kb = 0; kb < 512; kb += 64) {
    __syncthreads();
    stage_tile(B, Wbase + kb, 512, wave, lane);   // async, issued first
    stage_tile_cvt(A, x + (size_t)rowbase * 512 + kb, 512, wave, lane);
    __syncthreads();
    #pragma unroll
    for (int h = 0; h < 2; ++h) {
      const int slot0 = h * 4 + lg;
      f16x8 af[4], bf[4];
      #pragma unroll
      for (int g = 0; g < 4; ++g) {
        af[g] = lds_frag(A, wr * 64 + g * 16 + l15, slot0);
        bf[g] = lds_frag(B, wc * 64 + g * 16 + l15, slot0);
      }
      #pragma unroll
      for (int i = 0; i < 4; ++i)
        #pragma unroll
        for (int j = 0; j < 4; ++j)
          acc[i][j] = mfma_h(af[i], bf[j], acc[i][j]);
    }
  }

  if (which != 2) {
    f16_t* __restrict__ O = (which == 0) ? Q : K;
    const float* __restrict__ bb = (which == 0) ? bq : bk;
    #pragma unroll
    for (int j = 0; j < 4; ++j) {
      const int jl = jb + wc * 64 + j * 16 + l15;
      const float bias = bb[jl];
      #pragma unroll
      for (int i = 0; i < 4; ++i)
        #pragma unroll
        for (int r = 0; r < 4; ++r) {
          const int row = rowbase + wr * 64 + i * 16 + lg * 4 + r;
          O[(size_t)row * 512 + jl] = (f16_t)(acc[i][j][r] + bias);
        }
    }
  } else {
    __syncthreads();
    f16_t* vtl = (f16_t*)smem;          // [128][136] f16 = 34816 B
    #pragma unroll
    for (int j = 0; j < 4; ++j) {
      const int jj = wc * 64 + j * 16 + l15;
      const float bias = bv[jb + jj];
      #pragma unroll
      for (int i = 0; i < 4; ++i)
        #pragma unroll
        for (int r = 0; r < 4; ++r) {
          const int ii = wr * 64 + i * 16 + lg * 4 + r;
          vtl[jj * 136 + ii] = (f16_t)(acc[i][j][r] + bias);
        }
    }
    __syncthreads();
    const int dv = tid >> 1, hf = tid & 1;
    const int bat = rowbase >> 11, n0 = rowbase & 2047;
    f16_t* __restrict__ dst =
        &Vt[((size_t)bat * 512 + jb + dv) * 2048 + n0 + hf * 64];
    const f16_t* src = &vtl[dv * 136 + hf * 64];
    #pragma unroll
    for (int s = 0; s < 8; ++s)
      *(f16x8*)&dst[s * 8] = *(const f16x8*)&src[s * 8];
  }
}

// ---------------------------------------------------------------------------
// k_qk2: P_t = exp(QK^T - m_t) f16 per 64-col tile + m_t, l_t arrays.
// flat grid 2048: bat = wg>>8 (one batch per XCD), mt=(wg>>4)&15, nt=wg&15.
// Tile index t = nt*2 + wc.  mG/lG: [(bat*32 + t)*2048 + q_row].
// P is TILE-BLOCKED: P + ((bat*16+mt)*16+nt)*16384 is a [128][128] f16 tile.
// ---------------------------------------------------------------------------
__global__ __launch_bounds__(256, 4) void k_qk2(const f16_t* __restrict__ Q,
                                                const f16_t* __restrict__ K,
                                                f16_t* __restrict__ P,
                                                float* __restrict__ mG,
                                                float* __restrict__ lG)
{
  __shared__ __align__(16) unsigned char smem[34816];  // A+Bt staging / Pl
  f16_t* A  = (f16_t*)smem;
  f16_t* Bt = (f16_t*)(smem + 16384);

  const int wg = xcd_swz(blockIdx.x, 2048);
  const int bat = wg >> 8, mt = (wg >> 4) & 15, nt = wg & 15;
  const int tid = threadIdx.x, lane = tid & 63, wave = tid >> 6;
  const int wr = wave >> 1, wc = wave & 1, l15 = lane & 15, lg = lane >> 4;

  f32x4 acc[4][4] = {};
  const f16_t* Abase = Q + ((size_t)bat * 2048 + mt * 128) * 512;
  const f16_t* Bbase = K + ((size_t)bat * 2048 + nt * 128) * 512;

  for (int kb = 0; kb < 512; kb += 64) {
    __syncthreads();
    stage_tile(A, Abase + kb, 512, wave, lane);
    stage_tile(Bt, Bbase + kb, 512, wave, lane);
    __syncthreads();
    #pragma unroll
    for (int h = 0; h < 2; ++h) {
      const int slot0 = h * 4 + lg;
      f16x8 af[4], bf[4];
      #pragma unroll
      for (int g = 0; g < 4; ++g) {
        af[g] = lds_frag(A, wr * 64 + g * 16 + l15, slot0);
        bf[g] = lds_frag(Bt, wc * 64 + g * 16 + l15, slot0);
      }
      #pragma unroll
      for (int i = 0; i < 4; ++i)
        #pragma unroll
        for (int j = 0; j < 4; ++j)
          acc[i][j] = mfma_h(af[i], bf[j], acc[i][j]);
    }
  }

  // ---- fused epilogue: per-row max over this wave's 64 cols, exp, Pl
  //      write, f32 sum, m/l store. ----
  __syncthreads();              // all MFMA LDS reads done before Pl overlay
  f16_t* Pl = (f16_t*)smem;     // [128][136]
  const float LOG2E = 1.4426950408889634f;
  #pragma unroll
  for (int i = 0; i < 4; ++i)
    #pragma unroll
    for (int r = 0; r < 4; ++r) {
      const int rl = wr * 64 + i * 16 + lg * 4 + r;
      float mv = fmaxf(fmaxf(acc[i][0][r], acc[i][1][r]),
                       fmaxf(acc[i][2][r], acc[i][3][r]));
      mv = fmaxf(mv, __shfl_xor(mv, 1));
      mv = fmaxf(mv, __shfl_xor(mv, 2));
      mv = fmaxf(mv, __shfl_xor(mv, 4));
      mv = fmaxf(mv, __shfl_xor(mv, 8));
      float sum = 0.f;
      #pragma unroll
      for (int j = 0; j < 4; ++j) {
        const float e = __builtin_amdgcn_exp2f((acc[i][j][r] - mv) * LOG2E);
        Pl[rl * 136 + wc * 64 + j * 16 + l15] = (f16_t)e;
        sum += e;
      }
      sum += __shfl_xor(sum, 1);
      sum += __shfl_xor(sum, 2);
      sum += __shfl_xor(sum, 4);
      sum += __shfl_xor(sum, 8);
      if (l15 == 0) {
        const size_t idx =
            ((size_t)(bat * 32 + nt * 2 + wc)) * 2048 + mt * 128 + rl;
        mG[idx] = mv;
        lG[idx] = sum;
      }
    }
  __syncthreads();

  // tile-blocked P store: linear 32KB, 1KB contiguous per wave instruction
  {
    f16_t* __restrict__ dst =
        P + (((size_t)(bat * 16 + mt) * 16 + nt) << 14);
    const int c16 = tid & 15, r0 = tid >> 4;   // 16 rows per pass
    #pragma unroll
    for (int s = 0; s < 8; ++s) {
      const int row = s * 16 + r0;
      *(f16x8*)&dst[row * 128 + c16 * 8] =
          *(const f16x8*)&Pl[row * 136 + c16 * 8];
    }
  }
}

// ---------------------------------------------------------------------------
// k_pv7: out = (sum_t P_t f_t @ V) * sqrt(512)/l,  f_t = exp(m_t - M).
// flat grid 512 = bat(8,=XCD) x qt(32 x 64q) x dvh(2 x 256dv).  4 waves,
// each 64q x 64dv.  P staged from TILE-BLOCKED layout (gstride 128).
// ---------------------------------------------------------------------------
__global__ __launch_bounds__(256, 2) void k_pv7(const f16_t* __restrict__ P,
                                                const f16_t* __restrict__ Vt,
                                                const float* __restrict__ mG,
                                                const float* __restrict__ lG,
                                                float* __restrict__ out)
{
  __shared__ __align__(16) f16_t Pl[64 * 64];     // 8 KB
  __shared__ __align__(16) f16_t Vl[256 * 64];    // 32 KB
  __shared__ f16_t facL[64][34];                  // padded
  __shared__ float scrow[64];
  __shared__ float redp[64][4];

  const int id = blockIdx.x;
  const int bat = id & 7, qt = (id >> 3) & 31, dvh = id >> 8;
  const int tid = threadIdx.x, lane = tid & 63, wave = tid >> 6;
  const int l15 = lane & 15, lg = lane >> 4;
  const float LOG2E = 1.4426950408889634f;

  // ---- prologue: per-row M, facL[row][t] = exp(m_t-M) f16,
  //      scrow[row] = sqrt(512)/sum_t l_t*f_t ----
  {
    const int prow = tid >> 2, part = tid & 3;    // 8 tiles per thread
    float mt8[8], lt8[8];
    #pragma unroll
    for (int s = 0; s < 8; ++s) {
      const size_t idx =
          ((size_t)(bat * 32 + part * 8 + s)) * 2048 + qt * 64 + prow;
      mt8[s] = mG[idx];
      lt8[s] = lG[idx];
    }
    float mm = mt8[0];
    #pragma unroll
    for (int s = 1; s < 8; ++s) mm = fmaxf(mm, mt8[s]);
    redp[prow][part] = mm;
    __syncthreads();
    const float M = fmaxf(fmaxf(redp[prow][0], redp[prow][1]),
                          fmaxf(redp[prow][2], redp[prow][3]));
    __syncthreads();
    float ls = 0.f;
    #pragma unroll
    for (int s = 0; s < 8; ++s) {
      const float f = __builtin_amdgcn_exp2f((mt8[s] - M) * LOG2E);
      facL[prow][part * 8 + s] = (f16_t)f;
      ls += lt8[s] * f;
    }
    redp[prow][part] = ls;
    __syncthreads();
    if (part == 0)
      scrow[prow] = 22.62741699796952f /
                    (redp[prow][0] + redp[prow][1] + redp[prow][2] + redp[prow][3]);
  }

  const int mtq = qt >> 1;                 // P tile row index
  const int rowhalf = (qt & 1) * 64;       // row offset within tile
  const f16_t* Ptiles = P + (((size_t)(bat * 16 + mtq)) << 18);  // 16 tiles
  const f16_t* Vbase = Vt + ((size_t)bat * 512 + dvh * 256) * 2048;

  f32x4 acc[4][4] = {};

  for (int t = 0; t < 32; ++t) {
    __syncthreads();
    // P sub-tile [64q][64kv] from tile (mtq, nt=t>>1), cols (t&1)*64..
    const f16_t* psrc =
        Ptiles + ((size_t)(t >> 1) << 14) + rowhalf * 128 + (t & 1) * 64;
    stage_tile64(Pl, psrc, 128, wave, lane);
    stage_tile(Vl, Vbase + t * 64, 2048, wave, lane);
    stage_tile(Vl + 128 * 64, Vbase + (size_t)128 * 2048 + t * 64, 2048,
               wave, lane);
    __syncthreads();
    f16_t fv[4];
    #pragma unroll
    for (int g = 0; g < 4; ++g) fv[g] = facL[g * 16 + l15][t];
    #pragma unroll
    for (int ks = 0; ks < 2; ++ks) {
      const int slot0 = ks * 4 + lg;
      f16x8 af[4], bf[4];
      #pragma unroll
      for (int g = 0; g < 4; ++g) {
        af[g] = lds_frag(Pl, g * 16 + l15, slot0) * fv[g];
        bf[g] = lds_frag(Vl, wave * 64 + g * 16 + l15, slot0);
      }
      #pragma unroll
      for (int i = 0; i < 4; ++i)
        #pragma unroll
        for (int j = 0; j < 4; ++j)
          acc[i][j] = mfma_h(af[i], bf[j], acc[i][j]);
    }
  }

  #pragma unroll
  for (int i = 0; i < 4; ++i)
    #pragma unroll
    for (int r = 0; r < 4; ++r) {
      const int ql = i * 16 + lg * 4 + r;
      const float sc = scrow[ql];
      const size_t orow = ((size_t)bat * 2048 + qt * 64 + ql) * 512;
      #pragma unroll
      for (int j = 0; j < 4; ++j) {
        const int dv = dvh * 256 + wave * 64 + j * 16 + l15;
        out[orow + dv] = acc[i][j][r] * sc;
      }
    }
}

// ---------------------------------------------------------------------------
extern "C" void kernel_launch(void* const* d_in, const int* in_sizes, int n_in,
                              void* d_out, int out_size, void* d_ws, size_t ws_size,
                              hipStream_t stream) {
  const float* x  = (const float*)d_in[0];
  const float* Wq = (const float*)d_in[1];
  const float* bq = (const float*)d_in[2];
  const float* Wk = (const float*)d_in[3];
  const float* bk = (const float*)d_in[4];
  const float* Wv = (const float*)d_in[5];
  const float* bv = (const float*)d_in[6];
  float* out = (float*)d_out;

  char* ws = (char*)d_ws;
  f16_t* Q   = (f16_t*)(ws + 16777216);
  f16_t* K   = (f16_t*)(ws + 33554432);
  f16_t* Vt  = (f16_t*)(ws + 50331648);
  f16_t* P   = (f16_t*)(ws + 67108864);
  float* mG  = (float*)(ws + 134217728);
  float* lG  = (float*)(ws + 136314880);
  f16_t* Wt  = (f16_t*)(ws + 201326592);

  k_conv_w<<<dim3(8, 8, 3), 256, 0, stream>>>(Wq, Wk, Wv, Wt);
  k_proj<<<1536, 256, 0, stream>>>(x, Wt, bq, bk, bv, Q, K, Vt);
  k_qk2<<<2048, 256, 0, stream>>>(Q, K, P, mG, lG);
  k_pv7<<<512, 256, 0, stream>>>(P, Vt, mG, lG, out);
}

// Round 14
// 145.168 us; speedup vs baseline: 1.0473x; 1.0473x over previous
//
#include <hip/hip_runtime.h>
#include <stdint.h>
#include <stddef.h>

// ---------------------------------------------------------------------------
// out = softmax(x Wq+bq @ (x Wk+bk)^T) * sqrt(512) @ (x Wv+bv)
// B=8, N=2048, D=DK=DV=512, fp32 I/O.
// Round 14: revert to the round-12 best (146.1us). Structure: separate
// streaming conversions (x->f16, W->Wt f16); proj/qk2/pv7 GEMMs with
// global_load_lds + XOR-swizzled staging; tile-local softmax split
// (per-64-col m_t/l_t + tile-blocked P, factor fixup in pv); XCD pinning.
// ws layout (B): x16 0, Q 16777216, K 33554432, Vt 50331648,
//   P 67108864 (67108864), mG 134217728 (2097152), lG 136314880 (2097152),
//   Wt 201326592 (1572864).  total <= 202899456.
// ---------------------------------------------------------------------------

typedef _Float16 f16_t;
typedef _Float16 f16x8 __attribute__((ext_vector_type(8)));
typedef float    f32x4 __attribute__((ext_vector_type(4)));

__device__ __forceinline__ f32x4 mfma_h(f16x8 a, f16x8 b, f32x4 c) {
  // D frag: col = lane&15, row = (lane>>4)*4 + reg
  return __builtin_amdgcn_mfma_f32_16x16x32_f16(a, b, c, 0, 0, 0);
}

__device__ __forceinline__ void gl_lds16(const void* g, void* lds) {
  __builtin_amdgcn_global_load_lds(
      (const __attribute__((address_space(1))) unsigned int*)g,
      (__attribute__((address_space(3))) unsigned int*)lds, 16, 0, 0);
}

// Stage a [128][64] f16 tile (16 KB), 4-wave (256-thr) cooperative.
// Linear LDS dest; source pre-swizzled: phys slot s of row r holds logical
// slot s^(r&7) (16B slots, 8 per 128B row).
__device__ __forceinline__ void stage_tile(f16_t* lds, const f16_t* g,
                                           size_t gstride, int wave, int lane) {
  const int l8 = lane >> 3;
  const int lslot = (lane & 7) ^ l8;
  #pragma unroll
  for (int c = 0; c < 4; ++c) {
    const int chunk = wave * 4 + c;
    const int row = chunk * 8 + l8;
    gl_lds16(g + (size_t)row * gstride + lslot * 8, lds + chunk * 512);
  }
}

// Stage a [64][64] f16 tile (8 KB): 8 chunks, 2 per wave (256 thr).
__device__ __forceinline__ void stage_tile64(f16_t* lds, const f16_t* g,
                                             size_t gstride, int wave, int lane) {
  const int l8 = lane >> 3;
  const int lslot = (lane & 7) ^ l8;
  #pragma unroll
  for (int c = 0; c < 2; ++c) {
    const int chunk = wave * 2 + c;
    const int row = chunk * 8 + l8;
    gl_lds16(g + (size_t)row * gstride + lslot * 8, lds + chunk * 512);
  }
}

// Swizzled fragment read: logical (row R, 8 elems at col slot*8)
__device__ __forceinline__ f16x8 lds_frag(const f16_t* buf, int R, int slot) {
  return *(const f16x8*)&buf[R * 64 + (((slot ^ (R & 7)) & 7) << 3)];
}

// XCD-chunked work remap (requires nwg % 8 == 0)
__device__ __forceinline__ int xcd_swz(int id, int nwg) {
  return (id & 7) * (nwg >> 3) + (id >> 3);
}

// ---------------------------------------------------------------------------
__global__ __launch_bounds__(256) void k_conv_x(const float* __restrict__ x,
                                                f16_t* __restrict__ x16) {
  const int i = (blockIdx.x * 256 + threadIdx.x) * 8;
  const float4 a = *(const float4*)&x[i];
  const float4 b = *(const float4*)&x[i + 4];
  float v[8] = {a.x, a.y, a.z, a.w, b.x, b.y, b.z, b.w};
  f16x8 h;
  #pragma unroll
  for (int j = 0; j < 8; ++j) h[j] = (f16_t)v[j];
  *(f16x8*)&x16[i] = h;
}

// transpose+convert W -> Wt[p][n][k] f16
__global__ __launch_bounds__(256) void k_conv_w(const float* __restrict__ Wq,
                                                const float* __restrict__ Wk,
                                                const float* __restrict__ Wv,
                                                f16_t* __restrict__ Wt) {
  __shared__ float t[64][65];
  const int p = blockIdx.z;
  const float* __restrict__ W = (p == 0) ? Wq : (p == 1) ? Wk : Wv;
  const int n0 = blockIdx.x * 64, k0 = blockIdx.y * 64;
  const int tx = threadIdx.x & 63, ty = threadIdx.x >> 6;
  #pragma unroll
  for (int j = 0; j < 16; ++j)
    t[ty * 16 + j][tx] = W[(size_t)(k0 + ty * 16 + j) * 512 + n0 + tx];
  __syncthreads();
  #pragma unroll
  for (int j = 0; j < 16; ++j) {
    const int nl = ty * 16 + j;
    Wt[(size_t)p * 262144 + (size_t)(n0 + nl) * 512 + k0 + tx] =
        (f16_t)t[tx][nl];
  }
}

// ---------------------------------------------------------------------------
// Projection: flat grid 1536 (xcd-swizzled -> mt*12+jt).  Single fp16 MFMA.
// panels 0-3 Q, 4-7 K, 8-11 V (V transposed to Vt[b][dv][n]).
// ---------------------------------------------------------------------------
__global__ __launch_bounds__(256, 4) void k_proj(
    const f16_t* __restrict__ x16, const f16_t* __restrict__ Wt,
    const float* __restrict__ bq, const float* __restrict__ bk,
    const float* __restrict__ bv,
    f16_t* __restrict__ Q, f16_t* __restrict__ K, f16_t* __restrict__ Vt)
{
  __shared__ __align__(16) unsigned char smem[34816];  // A,B tiles / vtl
  f16_t* A = (f16_t*)smem;
  f16_t* B = (f16_t*)(smem + 16384);

  const int wg = xcd_swz(blockIdx.x, 1536);
  const int mt = wg / 12, jt = wg % 12;
  const int which = jt >> 2;            // 0=Q 1=K 2=V
  const int jb = (jt & 3) * 128;

  const int tid = threadIdx.x, lane = tid & 63, wave = tid >> 6;
  const int wr = wave >> 1, wc = wave & 1, l15 = lane & 15, lg = lane >> 4;
  const int rowbase = mt * 128;

  const f16_t* Wbase = Wt + (size_t)which * 262144 + (size_t)jb * 512;

  f32x4 acc[4][4] = {};

  for (int kb = 0; kb < 512; kb += 64) {
    __syncthreads();
    stage_tile(A, x16 + (size_t)rowbase * 512 + kb, 512, wave, lane);
    stage_tile(B, Wbase + kb, 512, wave, lane);
    __syncthreads();
    #pragma unroll
    for (int h = 0; h < 2; ++h) {
      const int slot0 = h * 4 + lg;
      f16x8 af[4], bf[4];
      #pragma unroll
      for (int g = 0; g < 4; ++g) {
        af[g] = lds_frag(A, wr * 64 + g * 16 + l15, slot0);
        bf[g] = lds_frag(B, wc * 64 + g * 16 + l15, slot0);
      }
      #pragma unroll
      for (int i = 0; i < 4; ++i)
        #pragma unroll
        for (int j = 0; j < 4; ++j)
          acc[i][j] = mfma_h(af[i], bf[j], acc[i][j]);
    }
  }

  if (which != 2) {
    f16_t* __restrict__ O = (which == 0) ? Q : K;
    const float* __restrict__ bb = (which == 0) ? bq : bk;
    #pragma unroll
    for (int j = 0; j < 4; ++j) {
      const int jl = jb + wc * 64 + j * 16 + l15;
      const float bias = bb[jl];
      #pragma unroll
      for (int i = 0; i < 4; ++i)
        #pragma unroll
        for (int r = 0; r < 4; ++r) {
          const int row = rowbase + wr * 64 + i * 16 + lg * 4 + r;
          O[(size_t)row * 512 + jl] = (f16_t)(acc[i][j][r] + bias);
        }
    }
  } else {
    __syncthreads();
    f16_t* vtl = (f16_t*)smem;          // [128][136] f16 = 34816 B
    #pragma unroll
    for (int j = 0; j < 4; ++j) {
      const int jj = wc * 64 + j * 16 + l15;
      const float bias = bv[jb + jj];
      #pragma unroll
      for (int i = 0; i < 4; ++i)
        #pragma unroll
        for (int r = 0; r < 4; ++r) {
          const int ii = wr * 64 + i * 16 + lg * 4 + r;
          vtl[jj * 136 + ii] = (f16_t)(acc[i][j][r] + bias);
        }
    }
    __syncthreads();
    const int dv = tid >> 1, hf = tid & 1;
    const int bat = rowbase >> 11, n0 = rowbase & 2047;
    f16_t* __restrict__ dst =
        &Vt[((size_t)bat * 512 + jb + dv) * 2048 + n0 + hf * 64];
    const f16_t* src = &vtl[dv * 136 + hf * 64];
    #pragma unroll
    for (int s = 0; s < 8; ++s)
      *(f16x8*)&dst[s * 8] = *(const f16x8*)&src[s * 8];
  }
}

// ---------------------------------------------------------------------------
// k_qk2: P_t = exp(QK^T - m_t) f16 per 64-col tile + m_t, l_t arrays.
// flat grid 2048: bat = wg>>8 (one batch per XCD), mt=(wg>>4)&15, nt=wg&15.
// Tile index t = nt*2 + wc.  mG/lG: [(bat*32 + t)*2048 + q_row].
// P is TILE-BLOCKED: P + ((bat*16+mt)*16+nt)*16384 is a [128][128] f16 tile.
// ---------------------------------------------------------------------------
__global__ __launch_bounds__(256, 4) void k_qk2(const f16_t* __restrict__ Q,
                                                const f16_t* __restrict__ K,
                                                f16_t* __restrict__ P,
                                                float* __restrict__ mG,
                                                float* __restrict__ lG)
{
  __shared__ __align__(16) unsigned char smem[34816];  // A+Bt staging / Pl
  f16_t* A  = (f16_t*)smem;
  f16_t* Bt = (f16_t*)(smem + 16384);

  const int wg = xcd_swz(blockIdx.x, 2048);
  const int bat = wg >> 8, mt = (wg >> 4) & 15, nt = wg & 15;
  const int tid = threadIdx.x, lane = tid & 63, wave = tid >> 6;
  const int wr = wave >> 1, wc = wave & 1, l15 = lane & 15, lg = lane >> 4;

  f32x4 acc[4][4] = {};
  const f16_t* Abase = Q + ((size_t)bat * 2048 + mt * 128) * 512;
  const f16_t* Bbase = K + ((size_t)bat * 2048 + nt * 128) * 512;

  for (int kb = 0; kb < 512; kb += 64) {
    __syncthreads();
    stage_tile(A, Abase + kb, 512, wave, lane);
    stage_tile(Bt, Bbase + kb, 512, wave, lane);
    __syncthreads();
    #pragma unroll
    for (int h = 0; h < 2; ++h) {
      const int slot0 = h * 4 + lg;
      f16x8 af[4], bf[4];
      #pragma unroll
      for (int g = 0; g < 4; ++g) {
        af[g] = lds_frag(A, wr * 64 + g * 16 + l15, slot0);
        bf[g] = lds_frag(Bt, wc * 64 + g * 16 + l15, slot0);
      }
      #pragma unroll
      for (int i = 0; i < 4; ++i)
        #pragma unroll
        for (int j = 0; j < 4; ++j)
          acc[i][j] = mfma_h(af[i], bf[j], acc[i][j]);
    }
  }

  // ---- fused epilogue: per-row max over this wave's 64 cols, exp, Pl
  //      write, f32 sum, m/l store. ----
  __syncthreads();              // all MFMA LDS reads done before Pl overlay
  f16_t* Pl = (f16_t*)smem;     // [128][136]
  const float LOG2E = 1.4426950408889634f;
  #pragma unroll
  for (int i = 0; i < 4; ++i)
    #pragma unroll
    for (int r = 0; r < 4; ++r) {
      const int rl = wr * 64 + i * 16 + lg * 4 + r;
      float mv = fmaxf(fmaxf(acc[i][0][r], acc[i][1][r]),
                       fmaxf(acc[i][2][r], acc[i][3][r]));
      mv = fmaxf(mv, __shfl_xor(mv, 1));
      mv = fmaxf(mv, __shfl_xor(mv, 2));
      mv = fmaxf(mv, __shfl_xor(mv, 4));
      mv = fmaxf(mv, __shfl_xor(mv, 8));
      float sum = 0.f;
      #pragma unroll
      for (int j = 0; j < 4; ++j) {
        const float e = __builtin_amdgcn_exp2f((acc[i][j][r] - mv) * LOG2E);
        Pl[rl * 136 + wc * 64 + j * 16 + l15] = (f16_t)e;
        sum += e;
      }
      sum += __shfl_xor(sum, 1);
      sum += __shfl_xor(sum, 2);
      sum += __shfl_xor(sum, 4);
      sum += __shfl_xor(sum, 8);
      if (l15 == 0) {
        const size_t idx =
            ((size_t)(bat * 32 + nt * 2 + wc)) * 2048 + mt * 128 + rl;
        mG[idx] = mv;
        lG[idx] = sum;
      }
    }
  __syncthreads();

  // tile-blocked P store: linear 32KB, 1KB contiguous per wave instruction
  {
    f16_t* __restrict__ dst =
        P + (((size_t)(bat * 16 + mt) * 16 + nt) << 14);
    const int c16 = tid & 15, r0 = tid >> 4;   // 16 rows per pass
    #pragma unroll
    for (int s = 0; s < 8; ++s) {
      const int row = s * 16 + r0;
      *(f16x8*)&dst[row * 128 + c16 * 8] =
          *(const f16x8*)&Pl[row * 136 + c16 * 8];
    }
  }
}

// ---------------------------------------------------------------------------
// k_pv7: out = (sum_t P_t f_t @ V) * sqrt(512)/l,  f_t = exp(m_t - M).
// flat grid 512 = bat(8,=XCD) x qt(32 x 64q) x dvh(2 x 256dv).  4 waves,
// each 64q x 64dv.  P staged from TILE-BLOCKED layout (gstride 128).
// ---------------------------------------------------------------------------
__global__ __launch_bounds__(256, 2) void k_pv7(const f16_t* __restrict__ P,
                                                const f16_t* __restrict__ Vt,
                                                const float* __restrict__ mG,
                                                const float* __restrict__ lG,
                                                float* __restrict__ out)
{
  __shared__ __align__(16) f16_t Pl[64 * 64];     // 8 KB
  __shared__ __align__(16) f16_t Vl[256 * 64];    // 32 KB
  __shared__ f16_t facL[64][34];                  // padded
  __shared__ float scrow[64];
  __shared__ float redp[64][4];

  const int id = blockIdx.x;
  const int bat = id & 7, qt = (id >> 3) & 31, dvh = id >> 8;
  const int tid = threadIdx.x, lane = tid & 63, wave = tid >> 6;
  const int l15 = lane & 15, lg = lane >> 4;
  const float LOG2E = 1.4426950408889634f;

  // ---- prologue: per-row M, facL[row][t] = exp(m_t-M) f16,
  //      scrow[row] = sqrt(512)/sum_t l_t*f_t ----
  {
    const int prow = tid >> 2, part = tid & 3;    // 8 tiles per thread
    float mt8[8], lt8[8];
    #pragma unroll
    for (int s = 0; s < 8; ++s) {
      const size_t idx =
          ((size_t)(bat * 32 + part * 8 + s)) * 2048 + qt * 64 + prow;
      mt8[s] = mG[idx];
      lt8[s] = lG[idx];
    }
    float mm = mt8[0];
    #pragma unroll
    for (int s = 1; s < 8; ++s) mm = fmaxf(mm, mt8[s]);
    redp[prow][part] = mm;
    __syncthreads();
    const float M = fmaxf(fmaxf(redp[prow][0], redp[prow][1]),
                          fmaxf(redp[prow][2], redp[prow][3]));
    __syncthreads();
    float ls = 0.f;
    #pragma unroll
    for (int s = 0; s < 8; ++s) {
      const float f = __builtin_amdgcn_exp2f((mt8[s] - M) * LOG2E);
      facL[prow][part * 8 + s] = (f16_t)f;
      ls += lt8[s] * f;
    }
    redp[prow][part] = ls;
    __syncthreads();
    if (part == 0)
      scrow[prow] = 22.62741699796952f /
                    (redp[prow][0] + redp[prow][1] + redp[prow][2] + redp[prow][3]);
  }

  const int mtq = qt >> 1;                 // P tile row index
  const int rowhalf = (qt & 1) * 64;       // row offset within tile
  const f16_t* Ptiles = P + (((size_t)(bat * 16 + mtq)) << 18);  // 16 tiles
  const f16_t* Vbase = Vt + ((size_t)bat * 512 + dvh * 256) * 2048;

  f32x4 acc[4][4] = {};

  for (int t = 0; t < 32; ++t) {
    __syncthreads();
    // P sub-tile [64q][64kv] from tile (mtq, nt=t>>1), cols (t&1)*64..
    const f16_t* psrc =
        Ptiles + ((size_t)(t >> 1) << 14) + rowhalf * 128 + (t & 1) * 64;
    stage_tile64(Pl, psrc, 128, wave, lane);
    stage_tile(Vl, Vbase + t * 64, 2048, wave, lane);
    stage_tile(Vl + 128 * 64, Vbase + (size_t)128 * 2048 + t * 64, 2048,
               wave, lane);
    __syncthreads();
    f16_t fv[4];
    #pragma unroll
    for (int g = 0; g < 4; ++g) fv[g] = facL[g * 16 + l15][t];
    #pragma unroll
    for (int ks = 0; ks < 2; ++ks) {
      const int slot0 = ks * 4 + lg;
      f16x8 af[4], bf[4];
      #pragma unroll
      for (int g = 0; g < 4; ++g) {
        af[g] = lds_frag(Pl, g * 16 + l15, slot0) * fv[g];
        bf[g] = lds_frag(Vl, wave * 64 + g * 16 + l15, slot0);
      }
      #pragma unroll
      for (int i = 0; i < 4; ++i)
        #pragma unroll
        for (int j = 0; j < 4; ++j)
          acc[i][j] = mfma_h(af[i], bf[j], acc[i][j]);
    }
  }

  #pragma unroll
  for (int i = 0; i < 4; ++i)
    #pragma unroll
    for (int r = 0; r < 4; ++r) {
      const int ql = i * 16 + lg * 4 + r;
      const float sc = scrow[ql];
      const size_t orow = ((size_t)bat * 2048 + qt * 64 + ql) * 512;
      #pragma unroll
      for (int j = 0; j < 4; ++j) {
        const int dv = dvh * 256 + wave * 64 + j * 16 + l15;
        out[orow + dv] = acc[i][j][r] * sc;
      }
    }
}

// ---------------------------------------------------------------------------
extern "C" void kernel_launch(void* const* d_in, const int* in_sizes, int n_in,
                              void* d_out, int out_size, void* d_ws, size_t ws_size,
                              hipStream_t stream) {
  const float* x  = (const float*)d_in[0];
  const float* Wq = (const float*)d_in[1];
  const float* bq = (const float*)d_in[2];
  const float* Wk = (const float*)d_in[3];
  const float* bk = (const float*)d_in[4];
  const float* Wv = (const float*)d_in[5];
  const float* bv = (const float*)d_in[6];
  float* out = (float*)d_out;

  char* ws = (char*)d_ws;
  f16_t* x16 = (f16_t*)(ws + 0);
  f16_t* Q   = (f16_t*)(ws + 16777216);
  f16_t* K   = (f16_t*)(ws + 33554432);
  f16_t* Vt  = (f16_t*)(ws + 50331648);
  f16_t* P   = (f16_t*)(ws + 67108864);
  float* mG  = (float*)(ws + 134217728);
  float* lG  = (float*)(ws + 136314880);
  f16_t* Wt  = (f16_t*)(ws + 201326592);

  k_conv_x<<<4096, 256, 0, stream>>>(x, x16);
  k_conv_w<<<dim3(8, 8, 3), 256, 0, stream>>>(Wq, Wk, Wv, Wt);
  k_proj<<<1536, 256, 0, stream>>>(x16, Wt, bq, bk, bv, Q, K, Vt);
  k_qk2<<<2048, 256, 0, stream>>>(Q, K, P, mG, lG);
  k_pv7<<<512, 256, 0, stream>>>(P, Vt, mG, lG, out);
}